// Round 4
// baseline (21072.012 us; speedup 1.0000x reference)
//
#include <hip/hip_runtime.h>
#include <hip/hip_bf16.h>

// Problem constants
#define Bb   128
#define Tt   800
#define Uu   64
#define Cc   80
#define Nn   512
#define KP   640      // K layout: [h 0..511 | x 512..514 | pad | w 544..623 | pad 624..639]
#define NBLK 128
#define KSTR 648      // ldsB row stride (shorts)
#define LBL  (16*KSTR) // lo-limb offset inside ldsB (shorts)
#define WWS  517      // ldsWw row stride (f32, odd -> conflict-free)

#define AL   (Bb*KP)   // amat limb stride (shorts) = 81920
#define ABUF (2*AL)    // amat buffer stride (shorts)
#define WL   (2048*KP) // wcb limb stride (shorts)

#define OUT_PHI 52428800u   // 128*800*512
#define OUT_W   58982400u   // + 128*800*64

// ws byte offsets
#define WS_WCB   0u         // 2 limb * 2048 * 640 * 2B = 5,242,880
#define WS_AMAT  5242880u   // 2 buf * 2 limb * 128 * 640 * 2B = 655,360
#define WS_WWT   5898240u   // [30][512] f32 = 61,440
#define WS_CTR   5959680u   // 18 * 32 ints = 2,304

typedef __attribute__((ext_vector_type(8))) short short8;
typedef __attribute__((ext_vector_type(4))) float f32x4;
typedef unsigned long long u64;

__device__ __forceinline__ float b2f(unsigned short u){ unsigned int i = ((unsigned int)u)<<16; float f; __builtin_memcpy(&f,&i,4); return f; }
__device__ __forceinline__ unsigned short f2b(float f){ __hip_bfloat16 h = __float2bfloat16(f); unsigned short u; __builtin_memcpy(&u,&h,2); return u; }
__device__ __forceinline__ float sigm(float v){ return 1.f/(1.f + expf(-v)); }

// MALL-coherent (agent-scope, relaxed) accessors
__device__ __forceinline__ u64 ald(const u64* p){ return __hip_atomic_load(p, __ATOMIC_RELAXED, __HIP_MEMORY_SCOPE_AGENT); }
__device__ __forceinline__ void ast2(unsigned short* p, unsigned short v){ __hip_atomic_store(p, v, __ATOMIC_RELAXED, __HIP_MEMORY_SCOPE_AGENT); }
__device__ __forceinline__ void drain_vm(){ asm volatile("s_waitcnt vmcnt(0)" ::: "memory"); }

// Tree barrier: 8 leaf counters (128B apart) + root. base[0]=root, leaf j at base+32*(1+j).
__device__ __forceinline__ void arrive_tree(int* base, int blk, int inst /*1-based*/) {
    int* leaf = base + 32*(1 + (blk & 7));
    int v = __hip_atomic_fetch_add(leaf, 1, __ATOMIC_RELAXED, __HIP_MEMORY_SCOPE_AGENT);
    if (v == inst*16 - 1)   // 16th arriver of this instance at this leaf
        __hip_atomic_fetch_add(base, 1, __ATOMIC_RELAXED, __HIP_MEMORY_SCOPE_AGENT);
}
__device__ __forceinline__ void wait_root(int* base, int target) {
    while (__hip_atomic_load(base, __ATOMIC_RELAXED, __HIP_MEMORY_SCOPE_AGENT) < target)
        __builtin_amdgcn_s_sleep(1);
}

// ---- prep: combined weights -> bf16 hi/lo limbs; W_win transpose (f32) ----
__global__ void prep_weights(const float* __restrict__ Wx, const float* __restrict__ Wh,
                             const float* __restrict__ Wwin,
                             unsigned short* __restrict__ wcb, float* __restrict__ wwt) {
    int i = blockIdx.x*256 + threadIdx.x;
    const int n1 = 2048*KP;                       // 1,310,720
    if (i < n1) {
        int col = i / KP, k = i % KP;
        float v;
        if (k < 512)      v = Wh[k*2048 + col];
        else if (k < 515) v = Wx[(k-512)*2048 + col];
        else if (k < 544) v = 0.f;
        else if (k < 624) v = Wx[(3 + (k-544))*2048 + col];
        else              v = 0.f;
        unsigned short hi = f2b(v);
        wcb[i]      = hi;
        wcb[WL + i] = f2b(v - b2f(hi));
    } else {
        int j = i - n1;
        if (j < 30*512) {
            int c = j >> 9, k = j & 511;
            wwt[j] = Wwin[k*30 + c];              // [c][k] f32
        }
    }
}

// ---- prep: A-matrix double-buffer (hi/lo), counters ----
__global__ void prep_state(const float* __restrict__ x, unsigned short* __restrict__ amat,
                           int* __restrict__ ctr) {
    int i = blockIdx.x*256 + threadIdx.x;
    const int n1 = 2*Bb*KP;           // 163,840 (buf, r, k)
    if (i < n1) {
        int buf = i / (Bb*KP);
        int r   = (i % (Bb*KP)) / KP;
        int k   = i % KP;
        float v = 0.f;
        if (buf == 0 && k >= 512 && k < 515) v = x[r*(Tt*3) + (k-512)];   // x[:,0,:]
        unsigned short hi = f2b(v);
        amat[buf*ABUF + r*KP + k]      = hi;
        amat[buf*ABUF + AL + r*KP + k] = f2b(v - b2f(hi));
    } else if (i < n1 + 18*32) {
        ctr[i - n1] = 0;
    }
}

__global__ __launch_bounds__(256, 1) void rnn_main(
    const float* __restrict__ x,      // [128][800][3]
    const float* __restrict__ sent,   // [128][64][80]
    const int*   __restrict__ slen,   // [128]
    const float* __restrict__ bias,   // [2048]
    const float* __restrict__ bwin,   // [30]
    const unsigned short* __restrict__ wcb,   // 2 limb x [2048][640]
    const float* __restrict__ wwt,            // [30][512] f32
    unsigned short* __restrict__ amat,        // 2 buf x 2 limb x [128][640]
    int* __restrict__ ctr,
    float* __restrict__ out)
{
    __shared__ unsigned short ldsB[2*16*KSTR]; // weight cols hi|lo  41,472 B
    __shared__ float ldsWw[30*WWS];            // W_win^T [c][k]     62,040 B
    __shared__ float ldsSent[Uu*Cc];           // sentence row f32   20,480 B
    __shared__ float ldsH[512];
    __shared__ float ldsWinP[256];
    __shared__ float ldsWin[32];
    __shared__ float ldsPhi[Uu];
    __shared__ float ldsBias[16];
    __shared__ float ldsBwin[32];
    __shared__ float ldsKap[16];

    const int blk  = blockIdx.x;
    const int tid  = threadIdx.x;
    const int wave = tid >> 6;
    const int lane = tid & 63;
    const int l15  = lane & 15;
    const int lhi  = lane >> 4;
    const int row  = blk;

    int* mroot = ctr;            // main barrier tree
    int* wroot = ctr + 32*9;     // w-exchange tree

    // ---- one-time LDS fills ----
    for (int idx = tid; idx < 16*80; idx += 256) {
        int cc = idx / 80, k8 = idx % 80;
        int col = (cc >> 2)*512 + blk*4 + (cc & 3);   // gate*512 + n
        *(short8*)&ldsB[cc*KSTR + k8*8]       = *(const short8*)&wcb[col*KP + k8*8];
        *(short8*)&ldsB[LBL + cc*KSTR + k8*8] = *(const short8*)&wcb[WL + col*KP + k8*8];
    }
    for (int idx = tid; idx < 30*512; idx += 256) {
        int c = idx >> 9, k = idx & 511;
        ldsWw[c*WWS + k] = wwt[idx];
    }
    for (int idx = tid; idx < Uu*Cc; idx += 256)
        ldsSent[idx] = sent[row*(Uu*Cc) + idx];
    if (tid < 16) ldsBias[tid] = bias[(tid>>2)*512 + blk*4 + (tid&3)];
    if (tid < 30) ldsBwin[tid] = bwin[tid];
    if (tid < 16) ldsKap[tid] = 0.f;
    __syncthreads();

    const int myLen = slen[row];
    float c_reg[2][4] = {{0.f,0.f,0.f,0.f},{0.f,0.f,0.f,0.f}};

    for (int i = 0; i < Tt; ++i) {
        const int p = i & 1;
        const unsigned short* aH  = amat + p*ABUF;
        const unsigned short* aLo = aH + AL;
        unsigned short* nH  = amat + (p^1)*ABUF;     // h_i destination
        unsigned short* nLo = nH + AL;
        unsigned short* wxH  = (unsigned short*)aH;  // w_{i-1}/x_i destination (same buffer)
        unsigned short* wxLo = wxH + AL;

        // ============ Phase B for step i-1 (h_{i-1} visible via last barrier) ============
        if (i >= 1) {
            if (tid < 128) {   // stage h row (hi+lo -> f32); k 0..511
                u64 vh = ald((const u64*)(aH  + row*KP) + tid);
                u64 vl = ald((const u64*)(aLo + row*KP) + tid);
                unsigned short ph[4], pl[4];
                __builtin_memcpy(ph, &vh, 8); __builtin_memcpy(pl, &vl, 8);
                #pragma unroll
                for (int j = 0; j < 4; ++j)
                    ldsH[tid*4 + j] = b2f(ph[j]) + b2f(pl[j]);
            }
            __syncthreads();
            {   // win partials
                int c = tid & 31, q = tid >> 5;
                if (c < 30) {
                    const float* wwc = &ldsWw[c*WWS + q*64];
                    const float* hh  = &ldsH[q*64];
                    float s = 0.f;
                    #pragma unroll
                    for (int k = 0; k < 64; ++k) s += hh[k]*wwc[k];
                    ldsWinP[q*32 + c] = s;
                }
            }
            __syncthreads();
            if (tid < 30) {
                float s = 0.f;
                #pragma unroll
                for (int q = 0; q < 8; ++q) s += ldsWinP[q*32 + tid];
                ldsWin[tid] = s + ldsBwin[tid];
            }
            __syncthreads();
            if (tid < 64) {                        // phi_{i-1}, u = tid
                float u1 = (float)tid + 1.0f;
                float phi = 0.f;
                #pragma unroll
                for (int k = 0; k < 10; ++k) {
                    float a  = expf(ldsWin[k]);
                    float be = expf(ldsWin[10+k]);
                    float kn = ldsKap[k] + expf(ldsWin[20+k]);
                    float d  = kn - u1;
                    phi += a * expf(-be * d * d);
                }
                if (tid >= myLen) phi = 0.f;
                ldsPhi[tid] = phi;
                out[OUT_PHI + (size_t)(row*Tt + (i-1))*Uu + tid] = phi;
                if (tid < 10)
                    ldsKap[tid] += expf(ldsWin[20+tid]);
            }
            __syncthreads();
            if (tid < 80) {                        // w_{i-1} -> k 544..623
                float s = 0.f;
                #pragma unroll
                for (int u = 0; u < Uu; ++u)
                    s += ldsPhi[u] * ldsSent[u*Cc + tid];
                out[OUT_W + (size_t)(row*Tt + (i-1))*Cc + tid] = s;
                unsigned short hb = f2b(s);
                ast2(wxH  + row*KP + 544 + tid, hb);
                ast2(wxLo + row*KP + 544 + tid, f2b(s - b2f(hb)));
            } else if (tid < 83) {                 // x_i -> k 512..514
                int j = tid - 80;
                float xv = x[((size_t)row*Tt + i)*3 + j];
                unsigned short hb = f2b(xv);
                ast2(wxH  + row*KP + 512 + j, hb);
                ast2(wxLo + row*KP + 512 + j, f2b(xv - b2f(hb)));
            }
            drain_vm();
            __syncthreads();
            if (tid == 0) arrive_tree(wroot, blk, i);
        }

        // ============ Phase A part 1: h-region MFMA (kt 0..15) ============
        f32x4 acc0[2], acc1[2];
        #pragma unroll
        for (int mi = 0; mi < 2; ++mi) {
            acc0[mi] = (f32x4){0.f,0.f,0.f,0.f};
            acc1[mi] = (f32x4){0.f,0.f,0.f,0.f};
            const int mt = wave*2 + mi;
            const u64* arH = (const u64*)(aH  + (mt*16 + l15)*KP) + lhi*2;
            const u64* arL = (const u64*)(aLo + (mt*16 + l15)*KP) + lhi*2;
            const unsigned short* brH = ldsB + l15*KSTR + lhi*8;
            const unsigned short* brL = ldsB + LBL + l15*KSTR + lhi*8;
            #pragma unroll
            for (int kt = 0; kt < 16; ++kt) {
                u64 a0 = ald(arH + kt*8), a1 = ald(arH + kt*8 + 1);
                u64 b0 = ald(arL + kt*8), b1 = ald(arL + kt*8 + 1);
                short8 ah, al;
                __builtin_memcpy(&ah, &a0, 8); __builtin_memcpy((char*)&ah + 8, &a1, 8);
                __builtin_memcpy(&al, &b0, 8); __builtin_memcpy((char*)&al + 8, &b1, 8);
                short8 bh = *(const short8*)(brH + kt*32);
                short8 bl = *(const short8*)(brL + kt*32);
                acc0[mi] = __builtin_amdgcn_mfma_f32_16x16x32_bf16(ah, bh, acc0[mi], 0, 0, 0);
                acc1[mi] = __builtin_amdgcn_mfma_f32_16x16x32_bf16(ah, bl, acc1[mi], 0, 0, 0);
                acc1[mi] = __builtin_amdgcn_mfma_f32_16x16x32_bf16(al, bh, acc1[mi], 0, 0, 0);
            }
        }

        // ============ wait for all rows' w_{i-1}/x_i (overlapped with part 1) ============
        if (tid == 0) wait_root(wroot, i*8);
        __syncthreads();

        // ============ Phase A part 2: x/w-region MFMA (kt 16..19) ============
        #pragma unroll
        for (int mi = 0; mi < 2; ++mi) {
            const int mt = wave*2 + mi;
            const u64* arH = (const u64*)(aH  + (mt*16 + l15)*KP) + lhi*2;
            const u64* arL = (const u64*)(aLo + (mt*16 + l15)*KP) + lhi*2;
            const unsigned short* brH = ldsB + l15*KSTR + lhi*8;
            const unsigned short* brL = ldsB + LBL + l15*KSTR + lhi*8;
            #pragma unroll
            for (int kt = 16; kt < 20; ++kt) {
                u64 a0 = ald(arH + kt*8), a1 = ald(arH + kt*8 + 1);
                u64 b0 = ald(arL + kt*8), b1 = ald(arL + kt*8 + 1);
                short8 ah, al;
                __builtin_memcpy(&ah, &a0, 8); __builtin_memcpy((char*)&ah + 8, &a1, 8);
                __builtin_memcpy(&al, &b0, 8); __builtin_memcpy((char*)&al + 8, &b1, 8);
                short8 bh = *(const short8*)(brH + kt*32);
                short8 bl = *(const short8*)(brL + kt*32);
                acc0[mi] = __builtin_amdgcn_mfma_f32_16x16x32_bf16(ah, bh, acc0[mi], 0, 0, 0);
                acc1[mi] = __builtin_amdgcn_mfma_f32_16x16x32_bf16(ah, bl, acc1[mi], 0, 0, 0);
                acc1[mi] = __builtin_amdgcn_mfma_f32_16x16x32_bf16(al, bh, acc1[mi], 0, 0, 0);
            }
        }

        // ============ gates -> h_i ============
        #pragma unroll
        for (int mi = 0; mi < 2; ++mi) {
            const int mt = wave*2 + mi;
            const float bv = ldsBias[l15];
            #pragma unroll
            for (int r = 0; r < 4; ++r) {
                float v   = acc0[mi][r] + acc1[mi][r] + bv;
                float t4  = __shfl_xor(v, 4);
                float t8  = __shfl_xor(v, 8);
                float t12 = __shfl_xor(v, 12);
                float ig = sigm(v), fg = sigm(t4), gg = tanhf(t8), og = sigm(t12);
                float cn = fg * c_reg[mi][r] + ig * gg;
                c_reg[mi][r] = cn;
                float h = og * tanhf(cn);
                if (l15 < 4) {
                    int br = mt*16 + lhi*4 + r;
                    int n  = blk*4 + l15;
                    unsigned short hb = f2b(h);
                    ast2(nH  + br*KP + n, hb);
                    ast2(nLo + br*KP + n, f2b(h - b2f(hb)));
                    out[(size_t)(br*Tt + i)*Nn + n] = h;
                }
            }
        }

        // ============ single grid barrier ============
        drain_vm();
        __syncthreads();
        if (tid == 0) {
            arrive_tree(mroot, blk, i+1);
            wait_root(mroot, (i+1)*8);
        }
        __syncthreads();
    }

    // ============ epilogue: phi/w for step 799 (h_799 in buffer 0) ============
    {
        const unsigned short* aH  = amat + 0*ABUF;
        const unsigned short* aLo = aH + AL;
        if (tid < 128) {
            u64 vh = ald((const u64*)(aH  + row*KP) + tid);
            u64 vl = ald((const u64*)(aLo + row*KP) + tid);
            unsigned short ph[4], pl[4];
            __builtin_memcpy(ph, &vh, 8); __builtin_memcpy(pl, &vl, 8);
            #pragma unroll
            for (int j = 0; j < 4; ++j)
                ldsH[tid*4 + j] = b2f(ph[j]) + b2f(pl[j]);
        }
        __syncthreads();
        {
            int c = tid & 31, q = tid >> 5;
            if (c < 30) {
                const float* wwc = &ldsWw[c*WWS + q*64];
                const float* hh  = &ldsH[q*64];
                float s = 0.f;
                #pragma unroll
                for (int k = 0; k < 64; ++k) s += hh[k]*wwc[k];
                ldsWinP[q*32 + c] = s;
            }
        }
        __syncthreads();
        if (tid < 30) {
            float s = 0.f;
            #pragma unroll
            for (int q = 0; q < 8; ++q) s += ldsWinP[q*32 + tid];
            ldsWin[tid] = s + ldsBwin[tid];
        }
        __syncthreads();
        if (tid < 64) {
            float u1 = (float)tid + 1.0f;
            float phi = 0.f;
            #pragma unroll
            for (int k = 0; k < 10; ++k) {
                float a  = expf(ldsWin[k]);
                float be = expf(ldsWin[10+k]);
                float kn = ldsKap[k] + expf(ldsWin[20+k]);
                float d  = kn - u1;
                phi += a * expf(-be * d * d);
            }
            if (tid >= myLen) phi = 0.f;
            ldsPhi[tid] = phi;
            out[OUT_PHI + (size_t)(row*Tt + 799)*Uu + tid] = phi;
        }
        __syncthreads();
        if (tid < 80) {
            float s = 0.f;
            #pragma unroll
            for (int u = 0; u < Uu; ++u)
                s += ldsPhi[u] * ldsSent[u*Cc + tid];
            out[OUT_W + (size_t)(row*Tt + 799)*Cc + tid] = s;
        }
    }
}

extern "C" void kernel_launch(void* const* d_in, const int* in_sizes, int n_in,
                              void* d_out, int out_size, void* d_ws, size_t ws_size,
                              hipStream_t stream) {
    (void)in_sizes; (void)n_in; (void)out_size; (void)ws_size;
    const float* x    = (const float*)d_in[0];
    const float* sent = (const float*)d_in[1];
    const int*   sl   = (const int*)d_in[2];
    const float* Wx   = (const float*)d_in[3];
    const float* Wh   = (const float*)d_in[4];
    const float* bias = (const float*)d_in[5];
    const float* Wwin = (const float*)d_in[6];
    const float* bwin = (const float*)d_in[7];

    char* ws = (char*)d_ws;
    unsigned short* wcb  = (unsigned short*)(ws + WS_WCB);
    unsigned short* amat = (unsigned short*)(ws + WS_AMAT);
    float* wwt = (float*)(ws + WS_WWT);
    int*   ctr = (int*)(ws + WS_CTR);
    float* out = (float*)d_out;

    {
        int total = 2048*KP + 30*512;
        prep_weights<<<(total + 255)/256, 256, 0, stream>>>(Wx, Wh, Wwin, wcb, wwt);
    }
    {
        int total = 2*Bb*KP + 18*32;
        prep_state<<<(total + 255)/256, 256, 0, stream>>>(x, amat, ctr);
    }
    rnn_main<<<NBLK, 256, 0, stream>>>(x, sent, sl, bias, bwin, wcb, wwt, amat, ctr, out);
}

// Round 6
// 18304.234 us; speedup vs baseline: 1.1512x; 1.1512x over previous
//
#include <hip/hip_runtime.h>
#include <hip/hip_bf16.h>

// Problem constants
#define Bb   128
#define Tt   800
#define Uu   64
#define Cc   80
#define Nn   512
#define KP   608      // K layout: [h 0..511 | x 512..514 | pad | w 520..599 | pad 600..607]
#define NBLK 128

#define AL   (Bb*KP)   // amat limb stride (shorts) = 77824
#define ABUF (2*AL)    // amat buffer stride (shorts)
#define WPP  491520    // wpart floats per buffer: 128*128*30

#define OUT_PHI 52428800u   // 128*800*512
#define OUT_W   58982400u   // + 128*800*64

// ws byte offsets (total 4,557,056 B — well under the 6.29 MB proven in R2)
#define WS_AMAT  0u         // 2 buf * 2 limb * 128*608 * 2B = 622,592
#define WS_WPART 622592u    // 2 * 128*128*30 * 4B = 3,932,160
#define WS_CTR   4554752u   // 18*32 ints = 2,304
#define WS_NEED  4557056u

typedef __attribute__((ext_vector_type(4))) int   i32x4;
typedef __attribute__((ext_vector_type(8))) short short8;
typedef __attribute__((ext_vector_type(4))) float f32x4;
typedef unsigned long long u64;

__device__ __forceinline__ float b2f(unsigned short u){ unsigned int i = ((unsigned int)u)<<16; float f; __builtin_memcpy(&f,&i,4); return f; }
__device__ __forceinline__ unsigned short f2b(float f){ __hip_bfloat16 h = __float2bfloat16(f); unsigned short u; __builtin_memcpy(&u,&h,2); return u; }
__device__ __forceinline__ float sigm(float v){ return 1.f/(1.f + __expf(-v)); }
__device__ __forceinline__ float tanh_(float v){ return 1.f - 2.f/(1.f + __expf(2.f*v)); }

// MALL-coherent (agent-scope, relaxed) accessors
__device__ __forceinline__ int  ald32(const int* p){ return __hip_atomic_load(p, __ATOMIC_RELAXED, __HIP_MEMORY_SCOPE_AGENT); }
__device__ __forceinline__ void ast2(unsigned short* p, unsigned short v){ __hip_atomic_store(p, v, __ATOMIC_RELAXED, __HIP_MEMORY_SCOPE_AGENT); }
__device__ __forceinline__ void ast8(u64* p, u64 v){ __hip_atomic_store(p, v, __ATOMIC_RELAXED, __HIP_MEMORY_SCOPE_AGENT); }
__device__ __forceinline__ void drain_vm(){ asm volatile("s_waitcnt vmcnt(0)" ::: "memory"); }

// 16B MALL-coherent load (bypass L1+L2)
__device__ __forceinline__ void gld16(i32x4* dst, const void* addr) {
  asm volatile("global_load_dwordx4 %0, %1, off sc0 sc1" : "=v"(*dst) : "v"(addr));
}
#define WAIT_VM(N) asm volatile("s_waitcnt vmcnt(" #N ")" ::: "memory")
__device__ __forceinline__ void wait_vm_n(int n) {
  if (n >= 20)      WAIT_VM(20);
  else if (n == 16) WAIT_VM(16);
  else if (n == 12) WAIT_VM(12);
  else if (n == 8)  WAIT_VM(8);
  else if (n == 4)  WAIT_VM(4);
  else              WAIT_VM(0);
}

// Tree barrier: root at base[0], 8 leaves at base[32*(1+j)]
__device__ __forceinline__ void arrive_tree(int* base, int blk, int inst /*1-based*/) {
    int* leaf = base + 32*(1 + (blk & 7));
    int v = __hip_atomic_fetch_add(leaf, 1, __ATOMIC_RELAXED, __HIP_MEMORY_SCOPE_AGENT);
    if (v == inst*16 - 1)
        __hip_atomic_fetch_add(base, 1, __ATOMIC_RELAXED, __HIP_MEMORY_SCOPE_AGENT);
}
__device__ __forceinline__ void wait_root(int* base, int target) {
    while (ald32(base) < target) __builtin_amdgcn_s_sleep(2);
}

// ---- prep: A-matrix double-buffer (hi/lo) + counters ----
__global__ void prep_state(const float* __restrict__ x, unsigned short* __restrict__ amat,
                           int* __restrict__ ctr) {
    int i = blockIdx.x*256 + threadIdx.x;
    const int n1 = 2*Bb*KP;           // (buf, r, k) = 155,648
    if (i < n1) {
        int buf = i / (Bb*KP);
        int r   = (i % (Bb*KP)) / KP;
        int k   = i % KP;
        float v = 0.f;
        if (buf == 0 && k >= 512 && k < 515) v = x[r*(Tt*3) + (k-512)];   // x[:,0,:]
        unsigned short hi = f2b(v);
        amat[buf*ABUF + r*KP + k]      = hi;
        amat[buf*ABUF + AL + r*KP + k] = f2b(v - b2f(hi));
    } else if (i < n1 + 18*32) {
        ctr[i - n1] = 0;
    }
}

__global__ __launch_bounds__(320, 1) void rnn_main(
    const float* __restrict__ x,      // [128][800][3]
    const float* __restrict__ sent,   // [128][64][80]
    const int*   __restrict__ slen,   // [128]
    const float* __restrict__ bias,   // [2048]
    const float* __restrict__ bwin,   // [30]
    const float* __restrict__ Wwin,   // [512][30]
    const float* __restrict__ Wx,     // [83][2048]
    const float* __restrict__ Wh,     // [512][2048]
    unsigned short* __restrict__ amat,        // 2 buf x 2 limb x [128][608]
    float* __restrict__ wpart,                // 2 x [128 br][128 blk][30]
    int* __restrict__ ctr,
    float* __restrict__ out)
{
    __shared__ unsigned short ldsBlo[19*512];  // B lo-limb frags [kt][lane][8]  19,456 B
    __shared__ float ldsSent[Uu*Cc];           // 20,480 B (wave4)
    __shared__ float ldsWpart[128*30];         // 15,360 B (wave4)
    __shared__ float ldsWin[32];
    __shared__ float ldsPhi[Uu];
    __shared__ float ldsKap[16];

    const int blk  = blockIdx.x;
    const int tid  = threadIdx.x;
    const int wave = tid >> 6;
    const int lane = tid & 63;
    const int l15  = lane & 15;
    const int lhi  = lane >> 4;

    int* hroot = ctr;            // h/wpart-ready tree
    int* wroot = ctr + 9*32;     // w/x-ready tree

    for (int idx = tid; idx < Uu*Cc; idx += 320)
        ldsSent[idx] = sent[blk*(Uu*Cc) + idx];
    if (tid < 16) ldsKap[tid] = 0.f;

    // ---- per-wave persistent state: weights loaded DIRECTLY from f32 ----
    short8 bfh[19];                     // B hi-limb: registers, loop-invariant
    float  bias_r = 0.f, ww0[4], ww1[4], bwin_r = 0.f;
    if (wave < 4) {
        const int colB = (l15 >> 2)*512 + blk*4 + (l15 & 3);   // gate*512 + n
        #pragma unroll
        for (int kt = 0; kt < 19; ++kt) {
            unsigned short hi8[8], lo8[8];
            #pragma unroll
            for (int j = 0; j < 8; ++j) {
                int k = kt*32 + lhi*8 + j;
                float v;
                if (k < 512)      v = Wh[k*2048 + colB];
                else if (k < 515) v = Wx[(k-512)*2048 + colB];
                else if (k < 520) v = 0.f;
                else if (k < 600) v = Wx[(3 + (k-520))*2048 + colB];
                else              v = 0.f;
                unsigned short hi = f2b(v);
                hi8[j] = hi; lo8[j] = f2b(v - b2f(hi));
            }
            __builtin_memcpy(&bfh[kt], hi8, 16);
            if (wave == 0) __builtin_memcpy(&ldsBlo[kt*512 + lane*8], lo8, 16);
        }
        bias_r = bias[colB];
        const int c0 = 2*l15;
        #pragma unroll
        for (int j = 0; j < 4; ++j) {
            ww0[j] = (c0   < 30) ? Wwin[(blk*4 + j)*30 + c0]     : 0.f;
            ww1[j] = (c0+1 < 30) ? Wwin[(blk*4 + j)*30 + c0 + 1] : 0.f;
        }
    } else {
        if (lane < 30) bwin_r = bwin[lane];
    }
    __syncthreads();

    const int myLen = slen[blk];
    float c_reg[2][4] = {{0.f,0.f,0.f,0.f},{0.f,0.f,0.f,0.f}};
    i32x4 abuf[6][4];

    // phase B for step tout (wave 4 only)
    auto phaseB = [&](int tout, const float* wp, bool doState, unsigned short* wdstH) {
        i32x4 tv[15];
        const char* wpb = (const char*)(wp + lane*60);
        #pragma unroll
        for (int j = 0; j < 15; ++j) gld16(&tv[j], wpb + j*16);
        WAIT_VM(0);
        __builtin_amdgcn_sched_barrier(0);
        #pragma unroll
        for (int j = 0; j < 15; ++j) {
            f32x4 f; __builtin_memcpy(&f, &tv[j], 16);
            *(f32x4*)&ldsWpart[lane*60 + j*4] = f;
        }
        asm volatile("s_waitcnt lgkmcnt(0)" ::: "memory");
        __builtin_amdgcn_sched_barrier(0);
        if (lane < 30) {
            float s0=0.f,s1=0.f,s2=0.f,s3=0.f;
            #pragma unroll
            for (int b = 0; b < 128; b += 4) {
                s0 += ldsWpart[(b+0)*30 + lane];
                s1 += ldsWpart[(b+1)*30 + lane];
                s2 += ldsWpart[(b+2)*30 + lane];
                s3 += ldsWpart[(b+3)*30 + lane];
            }
            ldsWin[lane] = (s0+s1)+(s2+s3) + bwin_r;
        }
        asm volatile("s_waitcnt lgkmcnt(0)" ::: "memory");
        __builtin_amdgcn_sched_barrier(0);
        float u1 = (float)lane + 1.0f;
        float phi = 0.f;
        #pragma unroll
        for (int k = 0; k < 10; ++k) {
            float a  = __expf(ldsWin[k]);
            float be = __expf(ldsWin[10+k]);
            float kn = ldsKap[k] + __expf(ldsWin[20+k]);
            float d  = kn - u1;
            phi += a * __expf(-be*d*d);
        }
        if (lane >= myLen) phi = 0.f;
        ldsPhi[lane] = phi;
        out[OUT_PHI + (size_t)(blk*Tt + tout)*Uu + lane] = phi;
        if (doState && lane < 10)
            ldsKap[lane] += __expf(ldsWin[20+lane]);
        asm volatile("s_waitcnt lgkmcnt(0)" ::: "memory");
        __builtin_amdgcn_sched_barrier(0);
        #pragma unroll
        for (int half = 0; half < 2; ++half) {
            int c = half*64 + lane;
            if (c < Cc) {
                float s = 0.f;
                #pragma unroll
                for (int u = 0; u < Uu; ++u) s += ldsPhi[u]*ldsSent[u*Cc + c];
                out[OUT_W + (size_t)(blk*Tt + tout)*Cc + c] = s;
                if (doState) {
                    unsigned short hb = f2b(s);
                    ast2(wdstH +      blk*KP + 520 + c, hb);
                    ast2(wdstH + AL + blk*KP + 520 + c, f2b(s - b2f(hb)));
                }
            }
        }
    };

    for (int i = 0; i < Tt; ++i) {
        const int p = i & 1;
        const unsigned short* aH  = amat + p*ABUF;
        const unsigned short* aLo = aH + AL;
        unsigned short* nH = amat + (p^1)*ABUF;

        // ---- single exposed sync: h_{i-1} + wpart_{i-1} ready ----
        __syncthreads();
        if (tid == 0) { arrive_tree(hroot, blk, i+1); wait_root(hroot, 8*(i+1)); }
        __syncthreads();

        if (wave < 4) {
            const int mt0 = wave*2, mt1 = wave*2 + 1;
            const char* a0Hb = (const char*)(aH  + (mt0*16 + l15)*KP + lhi*8);
            const char* a0Lb = (const char*)(aLo + (mt0*16 + l15)*KP + lhi*8);
            const char* a1Hb = (const char*)(aH  + (mt1*16 + l15)*KP + lhi*8);
            const char* a1Lb = (const char*)(aLo + (mt1*16 + l15)*KP + lhi*8);
            const unsigned short* bloB = ldsBlo + lane*8;
            f32x4 acc0[2], acc1[2];
            acc0[0] = (f32x4){0.f,0.f,0.f,0.f}; acc0[1] = (f32x4){0.f,0.f,0.f,0.f};
            acc1[0] = (f32x4){0.f,0.f,0.f,0.f}; acc1[1] = (f32x4){0.f,0.f,0.f,0.f};

            auto ISSUE = [&](int c) {   // chunk c: mi = c>>3, 2 kt, A hi+lo
                const int mi = c >> 3, slot = c % 6, kt0 = (c & 7)*2;
                const char* bH = mi ? a1Hb : a0Hb;
                const char* bL = mi ? a1Lb : a0Lb;
                gld16(&abuf[slot][0], bH + kt0*64);
                gld16(&abuf[slot][1], bH + kt0*64 + 64);
                gld16(&abuf[slot][2], bL + kt0*64);
                gld16(&abuf[slot][3], bL + kt0*64 + 64);
            };
            auto CONSUME = [&](int c) {
                const int mi = c >> 3, slot = c % 6, kt0 = (c & 7)*2;
                #pragma unroll
                for (int kk = 0; kk < 2; ++kk) {
                    const int kt = kt0 + kk;
                    short8 ah, al;
                    __builtin_memcpy(&ah, &abuf[slot][kk], 16);
                    __builtin_memcpy(&al, &abuf[slot][2+kk], 16);
                    short8 bl = *(const short8*)(bloB + kt*512);
                    acc0[mi] = __builtin_amdgcn_mfma_f32_16x16x32_bf16(ah, bfh[kt], acc0[mi], 0,0,0);
                    acc1[mi] = __builtin_amdgcn_mfma_f32_16x16x32_bf16(ah, bl,      acc1[mi], 0,0,0);
                    acc1[mi] = __builtin_amdgcn_mfma_f32_16x16x32_bf16(al, bfh[kt], acc1[mi], 0,0,0);
                }
            };

            // ---- phase 1: h-region (kt 0..15 per m-tile), 6-chunk-deep pipeline ----
            #pragma unroll
            for (int c = 0; c < 6; ++c) ISSUE(c);
            #pragma unroll
            for (int c = 0; c < 16; ++c) {
                wait_vm_n(c <= 9 ? 20 : (15-c)*4);
                __builtin_amdgcn_sched_barrier(0);
                CONSUME(c);
                if (c + 6 < 16) ISSUE(c + 6);
            }

            // ---- wait w_{i-1}/x_i (overlapped: wave4s ran during phase 1) ----
            if (lane == 0) {
                while (ald32(wroot) < 8*(i+1)) __builtin_amdgcn_s_sleep(2);
            }

            // ---- phase 2: x/w-region (kt 16..18) ----
            #pragma unroll
            for (int mi = 0; mi < 2; ++mi) {
                const char* bH = mi ? a1Hb : a0Hb;
                const char* bL = mi ? a1Lb : a0Lb;
                #pragma unroll
                for (int kk = 0; kk < 3; ++kk) {
                    gld16(&abuf[mi*3+kk][0], bH + (16+kk)*64);
                    gld16(&abuf[mi*3+kk][1], bL + (16+kk)*64);
                }
            }
            WAIT_VM(0);
            __builtin_amdgcn_sched_barrier(0);
            #pragma unroll
            for (int mi = 0; mi < 2; ++mi)
                #pragma unroll
                for (int kk = 0; kk < 3; ++kk) {
                    const int kt = 16 + kk;
                    short8 ah, al;
                    __builtin_memcpy(&ah, &abuf[mi*3+kk][0], 16);
                    __builtin_memcpy(&al, &abuf[mi*3+kk][1], 16);
                    short8 bl = *(const short8*)(bloB + kt*512);
                    acc0[mi] = __builtin_amdgcn_mfma_f32_16x16x32_bf16(ah, bfh[kt], acc0[mi], 0,0,0);
                    acc1[mi] = __builtin_amdgcn_mfma_f32_16x16x32_bf16(ah, bl,      acc1[mi], 0,0,0);
                    acc1[mi] = __builtin_amdgcn_mfma_f32_16x16x32_bf16(al, bfh[kt], acc1[mi], 0,0,0);
                }

            // ---- gates -> h_i, win-partials (from exact f32 h) ----
            #pragma unroll
            for (int mi = 0; mi < 2; ++mi) {
                #pragma unroll
                for (int r = 0; r < 4; ++r) {
                    float v   = acc0[mi][r] + acc1[mi][r] + bias_r;
                    float t4  = __shfl_xor(v, 4);
                    float t8  = __shfl_xor(v, 8);
                    float t12 = __shfl_xor(v, 12);
                    float ig = sigm(v), fg = sigm(t4), gg = tanh_(t8), og = sigm(t12);
                    float cn = fg*c_reg[mi][r] + ig*gg;
                    c_reg[mi][r] = cn;
                    float h = og*tanh_(cn);
                    const int br = (wave*2 + mi)*16 + lhi*4 + r;
                    if (l15 < 4) {
                        const int n = blk*4 + l15;
                        unsigned short hb = f2b(h);
                        ast2(nH +      br*KP + n, hb);
                        ast2(nH + AL + br*KP + n, f2b(h - b2f(hb)));
                        out[(size_t)(br*Tt + i)*Nn + n] = h;
                    }
                    float h0 = __shfl(h, (lane & ~15) | 0);
                    float h1 = __shfl(h, (lane & ~15) | 1);
                    float h2 = __shfl(h, (lane & ~15) | 2);
                    float h3 = __shfl(h, (lane & ~15) | 3);
                    if (l15 < 15) {
                        float p0 = h0*ww0[0] + h1*ww0[1] + h2*ww0[2] + h3*ww0[3];
                        float p1 = h0*ww1[0] + h1*ww1[1] + h2*ww1[2] + h3*ww1[3];
                        float2 f2v; f2v.x = p0; f2v.y = p1;
                        u64 pk; __builtin_memcpy(&pk, &f2v, 8);
                        ast8((u64*)(wpart + (size_t)(p^1)*WPP + br*3840 + blk*30 + 2*l15), pk);
                    }
                }
            }
            drain_vm();
        } else {
            // ---- wave 4: phase B for step i-1 + x prefetch ----
            if (i >= 1)
                phaseB(i-1, wpart + (size_t)p*WPP + blk*3840, true, amat + p*ABUF);
            if (i + 1 < Tt && lane < 3) {
                float xv = x[((size_t)blk*Tt + (i+1))*3 + lane];
                unsigned short hb = f2b(xv);
                ast2(nH +      blk*KP + 512 + lane, hb);
                ast2(nH + AL + blk*KP + 512 + lane, f2b(xv - b2f(hb)));
            }
            drain_vm();
            if (lane == 0) arrive_tree(wroot, blk, i+1);
        }
    }

    // ---- epilogue: phi/w for step 799 ----
    __syncthreads();
    if (tid == 0) { arrive_tree(hroot, blk, Tt+1); wait_root(hroot, 8*(Tt+1)); }
    __syncthreads();
    if (wave == 4)
        phaseB(Tt-1, wpart + (size_t)(Tt & 1)*WPP + blk*3840, false, nullptr);
}

extern "C" void kernel_launch(void* const* d_in, const int* in_sizes, int n_in,
                              void* d_out, int out_size, void* d_ws, size_t ws_size,
                              hipStream_t stream) {
    (void)in_sizes; (void)n_in; (void)out_size;
    if (ws_size < WS_NEED) return;   // clean fail instead of OOB fault
    const float* x    = (const float*)d_in[0];
    const float* sent = (const float*)d_in[1];
    const int*   sl   = (const int*)d_in[2];
    const float* Wx   = (const float*)d_in[3];
    const float* Wh   = (const float*)d_in[4];
    const float* bias = (const float*)d_in[5];
    const float* Wwin = (const float*)d_in[6];
    const float* bwin = (const float*)d_in[7];

    char* ws = (char*)d_ws;
    unsigned short* amat = (unsigned short*)(ws + WS_AMAT);
    float* wpart = (float*)(ws + WS_WPART);
    int*   ctr   = (int*)(ws + WS_CTR);
    float* out = (float*)d_out;

    {
        int total = 2*Bb*KP + 18*32;
        prep_state<<<(total + 255)/256, 256, 0, stream>>>(x, amat, ctr);
    }
    rnn_main<<<NBLK, 320, 0, stream>>>(x, sent, sl, bias, bwin, Wwin, Wx, Wh, amat, wpart, ctr, out);
}

// Round 8
// 17722.490 us; speedup vs baseline: 1.1890x; 1.0328x over previous
//
#include <hip/hip_runtime.h>
#include <hip/hip_bf16.h>

// Problem constants
#define Tt   800
#define Uu   64
#define Cc   80
#define GRP  16      // blocks per group (feature-split within group)
#define NGRP 8       // groups (batch-split): 8 x 16 rows = 128
#define NBLK 128
#define ASTR 648     // LDS A row stride in shorts (1296B = 81*16, bank-friendly)
#define ALIMB 10368  // 16*ASTR

// hbuf: [8 grp][2 buf][2 limb][16 row][512] shorts
#define HB_G    32768
#define HB_BUF  16384
#define HB_LIMB 8192
// wbuf: [8 grp][16 row][2 limb][96] shorts (pad 80->96, zeros persist)
#define WB_G 3072

#define OUT_PHI 52428800u   // 128*800*512
#define OUT_W   58982400u   // + 128*800*64

// ws byte offsets
#define WS_HBUF 0u          // 524,288
#define WS_WBUF 524288u     // 49,152
#define WS_FA   573440u     // 8*128B
#define WS_FB   574464u     // 8*128B
#define WS_NEED 575488u

typedef __attribute__((ext_vector_type(4))) int   i32x4;
typedef __attribute__((ext_vector_type(8))) short short8;
typedef __attribute__((ext_vector_type(4))) float f32x4;
typedef unsigned long long u64;

__device__ __forceinline__ float b2f(unsigned short u){ unsigned int i = ((unsigned int)u)<<16; float f; __builtin_memcpy(&f,&i,4); return f; }
__device__ __forceinline__ unsigned short f2b(float f){ __hip_bfloat16 h = __float2bfloat16(f); unsigned short u; __builtin_memcpy(&u,&h,2); return u; }
__device__ __forceinline__ float sigm(float v){ return 1.f/(1.f + __expf(-v)); }
__device__ __forceinline__ float tanh_(float v){ return 1.f - 2.f/(1.f + __expf(2.f*v)); }

// MALL-coherent (agent-scope relaxed -> sc0 sc1) accessors — R6-proven mechanism
__device__ __forceinline__ int  ald32(const int* p){ return __hip_atomic_load(p, __ATOMIC_RELAXED, __HIP_MEMORY_SCOPE_AGENT); }
__device__ __forceinline__ void ast32(int* p, int v){ __hip_atomic_store(p, v, __ATOMIC_RELAXED, __HIP_MEMORY_SCOPE_AGENT); }
__device__ __forceinline__ void ast2(unsigned short* p, unsigned short v){ __hip_atomic_store(p, v, __ATOMIC_RELAXED, __HIP_MEMORY_SCOPE_AGENT); }
__device__ __forceinline__ void drain_vm(){ asm volatile("s_waitcnt vmcnt(0)" ::: "memory"); }
#define WAIT_VM(N) asm volatile("s_waitcnt vmcnt(" #N ")" ::: "memory")

// 16B MALL-coherent load (bypass L1+L2) — R6-proven
__device__ __forceinline__ void gld16(i32x4* dst, const void* addr) {
  asm volatile("global_load_dwordx4 %0, %1, off sc0 sc1" : "=v"(*dst) : "v"(addr));
}

// intra-block soft barrier for waves 0-7 (wave8 never participates)
__device__ __forceinline__ void softbar(int* cnt, int target) {
  if ((threadIdx.x & 63) == 0)
    __hip_atomic_fetch_add(cnt, 1, __ATOMIC_RELEASE, __HIP_MEMORY_SCOPE_WORKGROUP);
  while (__hip_atomic_load(cnt, __ATOMIC_ACQUIRE, __HIP_MEMORY_SCOPE_WORKGROUP) < target)
    __builtin_amdgcn_s_sleep(1);
}

// ---- prep: zero hbuf, wbuf, flags ----
__global__ void prep(unsigned short* __restrict__ hbuf, unsigned short* __restrict__ wbuf,
                     int* __restrict__ fa, int* __restrict__ fb) {
  int i = blockIdx.x*256 + threadIdx.x;
  if (i < 262144) hbuf[i] = 0;
  else if (i < 262144 + 24576) wbuf[i - 262144] = 0;
  else if (i < 262144 + 24576 + 512) {
    int j = i - 262144 - 24576;
    if (j < 256) fa[j] = 0; else fb[j - 256] = 0;
  }
}

__global__ __launch_bounds__(576, 1) void rnn_main(
    const float* __restrict__ x,      // [128][800][3]
    const float* __restrict__ sent,   // [128][64][80]
    const int*   __restrict__ slen,   // [128]
    const float* __restrict__ bias,   // [2048]
    const float* __restrict__ bwin,   // [30]
    const float* __restrict__ Wwin,   // [512][30]
    const float* __restrict__ Wx,     // [83][2048]
    const float* __restrict__ Wh,     // [512][2048]
    unsigned short* __restrict__ hbuf,
    unsigned short* __restrict__ wbuf,
    int* __restrict__ fa,
    int* __restrict__ fb,
    float* __restrict__ out)
{
  __shared__ __align__(16) unsigned short lA[2*ALIMB];  // A hi|lo   41,472 B
  __shared__ __align__(16) float lWw[30*520];           // Wwin^T    62,400 B
  __shared__ float lSent[Uu*Cc];                        // own row   20,480 B
  __shared__ float lPhi[Uu];
  __shared__ int sb1, sb2, sb3;

  const int g    = blockIdx.x >> 4;
  const int jj   = blockIdx.x & 15;       // block index in group == owned row
  const int grow = g*16 + jj;             // global batch row owned (phase B)
  const int tid  = threadIdx.x;
  const int wave = tid >> 6;
  const int lane = tid & 63;
  const int l15  = lane & 15, lhi = lane >> 4;

  int* faG = fa + g*32;
  int* fbG = fb + g*32;
  unsigned short* hbG = hbuf + g*HB_G;
  unsigned short* wbG = wbuf + g*WB_G;

  // ---- one-time LDS fills ----
  for (int i = tid; i < 2*ALIMB/4; i += 576) ((u64*)lA)[i] = 0;     // zero A (pads persist)
  for (int i = tid; i < 512*30; i += 576) { int k = i/30, c = i%30; lWw[c*520 + k] = Wwin[i]; }
  for (int i = tid; i < Uu*Cc; i += 576) lSent[i] = sent[(size_t)grow*(Uu*Cc) + i];
  if (tid == 0) { sb1 = 0; sb2 = 0; sb3 = 0; }

  // ---- per-wave persistent state ----
  short8 bfh[20], bfl[20];    // weight fragments (waves 0-7): registers, loop-invariant
  float bias_r = 0.f;
  float bw[30], kapr[10];
  int myLen = 0;
  if (wave < 8) {
    const int zc = (l15>>2)*512 + jj*32 + wave*4 + (l15&3);   // gate*512 + unit
    #pragma unroll
    for (int kt = 0; kt < 20; ++kt) {
      unsigned short h8[8], l8[8];
      #pragma unroll
      for (int j2 = 0; j2 < 8; ++j2) {
        int k = kt*32 + lhi*8 + j2;
        float v;
        if (k < 512)      v = Wh[(size_t)k*2048 + zc];
        else if (k < 515) v = Wx[(size_t)(k-512)*2048 + zc];
        else if (k < 544) v = 0.f;
        else if (k < 624) v = Wx[(size_t)(3 + (k-544))*2048 + zc];
        else              v = 0.f;
        unsigned short hh = f2b(v);
        h8[j2] = hh; l8[j2] = f2b(v - b2f(hh));
      }
      __builtin_memcpy(&bfh[kt], h8, 16);
      __builtin_memcpy(&bfl[kt], l8, 16);
    }
    bias_r = bias[zc];
  } else {
    #pragma unroll
    for (int c2 = 0; c2 < 30; ++c2) bw[c2] = bwin[c2];
    #pragma unroll
    for (int k2 = 0; k2 < 10; ++k2) kapr[k2] = 0.f;
    myLen = slen[grow];
  }
  __syncthreads();

  float c_reg[4] = {0.f,0.f,0.f,0.f};

  // phase B for output step t-1 (wave 8 only); t in [1..800]
  auto phaseB = [&](int t) {
    // wait: all blocks stored h_{t-1}
    for (;;) { int v = ald32(&faG[lane & 15]); if (__all(v >= t)) break; __builtin_amdgcn_s_sleep(1); }
    // own-row h (hi+lo) from hbuf
    i32x4 vh, vl;
    gld16(&vh, hbG + (t&1)*HB_BUF + jj*512 + lane*8);
    gld16(&vl, hbG + (t&1)*HB_BUF + HB_LIMB + jj*512 + lane*8);
    WAIT_VM(0); __builtin_amdgcn_sched_barrier(0);
    unsigned short hh8[8], ll8[8];
    __builtin_memcpy(hh8, &vh, 16); __builtin_memcpy(ll8, &vl, 16);
    float hrow[8];
    #pragma unroll
    for (int i2 = 0; i2 < 8; ++i2) hrow[i2] = b2f(hh8[i2]) + b2f(ll8[i2]);
    // win partials (lane covers k = lane*8..+7) then butterfly all-reduce
    float p[30];
    #pragma unroll
    for (int c2 = 0; c2 < 30; ++c2) {
      float4 w0 = *(const float4*)&lWw[c2*520 + lane*8];
      float4 w1 = *(const float4*)&lWw[c2*520 + lane*8 + 4];
      p[c2] = hrow[0]*w0.x + hrow[1]*w0.y + hrow[2]*w0.z + hrow[3]*w0.w
            + hrow[4]*w1.x + hrow[5]*w1.y + hrow[6]*w1.z + hrow[7]*w1.w;
    }
    #pragma unroll
    for (int c2 = 0; c2 < 30; ++c2) {
      float s = p[c2];
      s += __shfl_xor(s, 1);  s += __shfl_xor(s, 2);  s += __shfl_xor(s, 4);
      s += __shfl_xor(s, 8);  s += __shfl_xor(s, 16); s += __shfl_xor(s, 32);
      p[c2] = s + bw[c2];
    }
    // phi over u = lane
    float u1 = (float)lane + 1.0f;
    float phi = 0.f;
    #pragma unroll
    for (int k2 = 0; k2 < 10; ++k2) {
      float a  = __expf(p[k2]);
      float be = __expf(p[10+k2]);
      float kn = kapr[k2] + __expf(p[20+k2]);
      float d  = kn - u1;
      phi += a * __expf(-be*d*d);
    }
    if (lane >= myLen) phi = 0.f;
    lPhi[lane] = phi;
    out[OUT_PHI + ((size_t)grow*Tt + (t-1))*Uu + lane] = phi;
    #pragma unroll
    for (int k2 = 0; k2 < 10; ++k2) kapr[k2] += __expf(p[20+k2]);
    asm volatile("s_waitcnt lgkmcnt(0)" ::: "memory");
    __builtin_amdgcn_sched_barrier(0);
    // w = phi . sent  -> out + wbuf (hi/lo)
    #pragma unroll
    for (int half = 0; half < 2; ++half) {
      int c2 = half*64 + lane;
      if (c2 < Cc) {
        float s = 0.f;
        #pragma unroll 8
        for (int u = 0; u < Uu; ++u) s += lPhi[u]*lSent[u*Cc + c2];
        out[OUT_W + ((size_t)grow*Tt + (t-1))*Cc + c2] = s;
        unsigned short w16 = f2b(s);
        ast2(wbG + jj*192 + c2, w16);
        ast2(wbG + jj*192 + 96 + c2, f2b(s - b2f(w16)));
      }
    }
    drain_vm();
    ast32(&fbG[jj], t);       // w_{t-1} ready
  };

  for (int t = 0; t < Tt; ++t) {
    if (wave == 8) {
      if (t == 0) ast32(&fbG[jj], 0);   // w_{-1}=0 pre-zeroed; just no-op keep-alive
      else phaseB(t);
      continue;
    }
    // ================= waves 0-7 =================
    if (t > 0) {
      for (;;) { int v = ald32(&faG[lane & 15]); if (__all(v >= t)) break; __builtin_amdgcn_s_sleep(1); }
    }
    // stage h_{t-1} (hi+lo) group-wide into LDS A
    {
      const unsigned short* hb = hbG + (t&1)*HB_BUF;
      const int r0 = tid >> 6;       // 0..7 (tid<512 here)
      const int q0 = lane;           // 0..63
      i32x4 va, vb, vc, vd;
      gld16(&va, hb + r0*512 + q0*8);
      gld16(&vb, hb + (r0+8)*512 + q0*8);
      gld16(&vc, hb + HB_LIMB + r0*512 + q0*8);
      gld16(&vd, hb + HB_LIMB + (r0+8)*512 + q0*8);
      WAIT_VM(0); __builtin_amdgcn_sched_barrier(0);
      *(i32x4*)&lA[r0*ASTR + q0*8]             = va;
      *(i32x4*)&lA[(r0+8)*ASTR + q0*8]         = vb;
      *(i32x4*)&lA[ALIMB + r0*ASTR + q0*8]     = vc;
      *(i32x4*)&lA[ALIMB + (r0+8)*ASTR + q0*8] = vd;
    }
    // x_t -> LDS A (k 512..514)
    if (tid < 48) {
      int row = tid / 3, comp = tid % 3;
      float xv = x[((size_t)(g*16 + row)*Tt + t)*3 + comp];
      unsigned short hh = f2b(xv);
      lA[row*ASTR + 512 + comp]         = hh;
      lA[ALIMB + row*ASTR + 512 + comp] = f2b(xv - b2f(hh));
    }
    softbar(&sb1, 8*(t+1));

    // MFMA h+x region (kt 0..16)
    f32x4 acc0 = {0.f,0.f,0.f,0.f}, acc1 = {0.f,0.f,0.f,0.f};
    const int arow = l15*ASTR + lhi*8;
    #pragma unroll
    for (int kt = 0; kt < 17; ++kt) {
      short8 ah = *(const short8*)&lA[arow + kt*32];
      short8 al = *(const short8*)&lA[ALIMB + arow + kt*32];
      acc0 = __builtin_amdgcn_mfma_f32_16x16x32_bf16(ah, bfh[kt], acc0, 0,0,0);
      acc1 = __builtin_amdgcn_mfma_f32_16x16x32_bf16(ah, bfl[kt], acc1, 0,0,0);
      acc1 = __builtin_amdgcn_mfma_f32_16x16x32_bf16(al, bfh[kt], acc1, 0,0,0);
    }

    // wait w_{t-1} from all 16 owners (overlapped with the 17-kt MFMA above)
    for (;;) { int v = ald32(&fbG[lane & 15]); if (__all(v >= t)) break; __builtin_amdgcn_s_sleep(1); }
    // stage w_{t-1} (hi+lo, 96-short rows incl zero pad) into LDS A (k 544..639)
    if (tid < 384) {
      int row = tid / 24, rem = tid % 24, limb = rem / 12, q = rem % 12;
      i32x4 v;
      gld16(&v, wbG + row*192 + limb*96 + q*8);
      WAIT_VM(0); __builtin_amdgcn_sched_barrier(0);
      *(i32x4*)&lA[limb*ALIMB + row*ASTR + 544 + q*8] = v;
    }
    softbar(&sb2, 8*(t+1));

    // MFMA w region (kt 17..19)
    #pragma unroll
    for (int kt = 17; kt < 20; ++kt) {
      short8 ah = *(const short8*)&lA[arow + kt*32];
      short8 al = *(const short8*)&lA[ALIMB + arow + kt*32];
      acc0 = __builtin_amdgcn_mfma_f32_16x16x32_bf16(ah, bfh[kt], acc0, 0,0,0);
      acc1 = __builtin_amdgcn_mfma_f32_16x16x32_bf16(ah, bfl[kt], acc1, 0,0,0);
      acc1 = __builtin_amdgcn_mfma_f32_16x16x32_bf16(al, bfh[kt], acc1, 0,0,0);
    }

    // gates -> h_t
    {
      unsigned short* hbn = hbG + ((t+1)&1)*HB_BUF;
      #pragma unroll
      for (int r = 0; r < 4; ++r) {
        float v   = acc0[r] + acc1[r] + bias_r;
        float t4  = __shfl_xor(v, 4);
        float t8  = __shfl_xor(v, 8);
        float t12 = __shfl_xor(v, 12);
        float ig = sigm(v), fg = sigm(t4), gg = tanh_(t8), og = sigm(t12);
        float cn = fg*c_reg[r] + ig*gg;
        c_reg[r] = cn;
        float h = og*tanh_(cn);
        if (l15 < 4) {
          int u  = jj*32 + wave*4 + l15;
          int rr = lhi*4 + r;
          unsigned short h16 = f2b(h);
          ast2(hbn + rr*512 + u, h16);
          ast2(hbn + HB_LIMB + rr*512 + u, f2b(h - b2f(h16)));
          out[((size_t)(g*16 + rr)*Tt + t)*512 + u] = h;
        }
      }
    }
    drain_vm();
    softbar(&sb3, 8*(t+1));
    if (tid == 0) ast32(&faG[jj], t+1);   // h_t ready
  }

  // epilogue: phi/w for t=799
  if (wave == 8) phaseB(Tt);
}

extern "C" void kernel_launch(void* const* d_in, const int* in_sizes, int n_in,
                              void* d_out, int out_size, void* d_ws, size_t ws_size,
                              hipStream_t stream) {
  (void)in_sizes; (void)n_in; (void)out_size;
  if (ws_size < WS_NEED) return;
  const float* x    = (const float*)d_in[0];
  const float* sent = (const float*)d_in[1];
  const int*   sl   = (const int*)d_in[2];
  const float* Wx   = (const float*)d_in[3];
  const float* Wh   = (const float*)d_in[4];
  const float* bias = (const float*)d_in[5];
  const float* Wwin = (const float*)d_in[6];
  const float* bwin = (const float*)d_in[7];

  char* ws = (char*)d_ws;
  unsigned short* hbuf = (unsigned short*)(ws + WS_HBUF);
  unsigned short* wbuf = (unsigned short*)(ws + WS_WBUF);
  int* fa = (int*)(ws + WS_FA);
  int* fb = (int*)(ws + WS_FB);
  float* out = (float*)d_out;

  prep<<<1122, 256, 0, stream>>>(hbuf, wbuf, fa, fb);
  rnn_main<<<NBLK, 576, 0, stream>>>(x, sent, sl, bias, bwin, Wwin, Wx, Wh,
                                     hbuf, wbuf, fa, fb, out);
}

// Round 10
// 17236.681 us; speedup vs baseline: 1.2225x; 1.0282x over previous
//
#include <hip/hip_runtime.h>
#include <hip/hip_bf16.h>

// Problem constants
#define Tt   800
#define Uu   64
#define Cc   80
#define NBLK 128
#define ASTR 648     // LDS A row stride in shorts
#define ALIMB 10368  // 16*ASTR

// hbuf: [8 grp][2 buf][2 limb][16 row][512] shorts
#define HB_G    32768
#define HB_BUF  16384
#define HB_LIMB 8192
// wbuf: [8 grp][16 row][192] shorts ([0..95]=hi, [96..191]=lo, pads zero)
#define WB_G 3072

#define OUT_PHI 52428800u   // 128*800*512
#define OUT_W   58982400u   // + 128*800*64

// ws byte offsets
#define WS_HBUF 0u          // 524,288
#define WS_WBUF 524288u     // 49,152
#define WS_FA   573440u     // 256 ints: ha counter at [g*32]
#define WS_FB   574464u     // 256 ints: wa counter at [g*32]
#define WS_NEED 575488u

typedef __attribute__((ext_vector_type(4))) int   i32x4;
typedef __attribute__((ext_vector_type(8))) short short8;
typedef __attribute__((ext_vector_type(4))) float f32x4;
typedef unsigned long long u64;

__device__ __forceinline__ float b2f(unsigned short u){ unsigned int i = ((unsigned int)u)<<16; float f; __builtin_memcpy(&f,&i,4); return f; }
__device__ __forceinline__ unsigned short f2b(float f){ __hip_bfloat16 h = __float2bfloat16(f); unsigned short u; __builtin_memcpy(&u,&h,2); return u; }
__device__ __forceinline__ float sigm(float v){ return 1.f/(1.f + __expf(-v)); }
__device__ __forceinline__ float tanh_(float v){ return 1.f - 2.f/(1.f + __expf(2.f*v)); }

// MALL-coherent ops (agent-scope relaxed -> sc0 sc1) — R6/R8-proven mechanism
__device__ __forceinline__ int  ald32(const int* p){ return __hip_atomic_load(p, __ATOMIC_RELAXED, __HIP_MEMORY_SCOPE_AGENT); }
__device__ __forceinline__ void aadd32(int* p){ __hip_atomic_fetch_add(p, 1, __ATOMIC_RELAXED, __HIP_MEMORY_SCOPE_AGENT); }
__device__ __forceinline__ void drain_vm(){ asm volatile("s_waitcnt vmcnt(0)" ::: "memory"); }
#define WAIT_VM(N) asm volatile("s_waitcnt vmcnt(" #N ")" ::: "memory")

__device__ __forceinline__ void gld16(i32x4* dst, const void* addr) {
  asm volatile("global_load_dwordx4 %0, %1, off sc0 sc1" : "=v"(*dst) : "v"(addr));
}
__device__ __forceinline__ void gst16(void* addr, i32x4 v) {
  asm volatile("global_store_dwordx4 %0, %1, off sc0 sc1" :: "v"(addr), "v"(v) : "memory");
}

// intra-block soft barrier for waves 0-7 (LDS counter; wave8 never participates)
__device__ __forceinline__ void softbar(int* cnt, int target) {
  if ((threadIdx.x & 63) == 0)
    __hip_atomic_fetch_add(cnt, 1, __ATOMIC_RELEASE, __HIP_MEMORY_SCOPE_WORKGROUP);
  while (__hip_atomic_load(cnt, __ATOMIC_ACQUIRE, __HIP_MEMORY_SCOPE_WORKGROUP) < target)
    __builtin_amdgcn_s_sleep(1);
}

// ---- prep: zero hbuf, wbuf, counters ----
__global__ void prep(unsigned short* __restrict__ hbuf, unsigned short* __restrict__ wbuf,
                     int* __restrict__ fa, int* __restrict__ fb) {
  int i = blockIdx.x*256 + threadIdx.x;
  if (i < 262144) hbuf[i] = 0;
  else if (i < 286720) wbuf[i - 262144] = 0;
  else if (i < 286976) fa[i - 286720] = 0;
  else if (i < 287232) fb[i - 286976] = 0;
}

__global__ __launch_bounds__(576, 1) void rnn_main(
    const float* __restrict__ x,      // [128][800][3]
    const float* __restrict__ sent,   // [128][64][80]
    const int*   __restrict__ slen,   // [128]
    const float* __restrict__ bias,   // [2048]
    const float* __restrict__ bwin,   // [30]
    const float* __restrict__ Wwin,   // [512][30]
    const float* __restrict__ Wx,     // [83][2048]
    const float* __restrict__ Wh,     // [512][2048]
    unsigned short* __restrict__ hbuf,
    unsigned short* __restrict__ wbuf,
    int* __restrict__ fa,
    int* __restrict__ fb,
    float* __restrict__ out)
{
  __shared__ __align__(16) unsigned short lA[2*ALIMB];     // A hi|lo   41,472 B
  __shared__ __align__(16) float lWw[30*520];              // Wwin^T    62,400 B
  __shared__ float lSent[Uu*Cc];                           // own row   20,480 B
  __shared__ float lPhi[Uu];
  __shared__ __align__(16) unsigned short lHout[2*16*32];  // h staging  2,048 B
  __shared__ __align__(16) unsigned short lWout[192];      // w staging    384 B
  __shared__ int sb0, sb1, sb2, sb3, sb4, sb5;

  const int g    = blockIdx.x >> 4;
  const int jj   = blockIdx.x & 15;       // block index in group == owned row
  const int grow = g*16 + jj;
  const int tid  = threadIdx.x;
  const int wave = tid >> 6;
  const int lane = tid & 63;
  const int l15  = lane & 15, lhi = lane >> 4;

  int* haC = fa + g*32;       // h arrive counter (one line per group)
  int* waC = fb + g*32;       // w arrive counter
  unsigned short* hbG = hbuf + g*HB_G;
  unsigned short* wbG = wbuf + g*WB_G;

  // ---- one-time LDS fills ----
  for (int i = tid; i < 2*ALIMB/4; i += 576) ((u64*)lA)[i] = 0;
  for (int i = tid; i < 512*30; i += 576) { int k = i/30, c = i%30; lWw[c*520 + k] = Wwin[i]; }
  for (int i = tid; i < Uu*Cc; i += 576) lSent[i] = sent[(size_t)grow*(Uu*Cc) + i];
  for (int i = tid; i < 192; i += 576) lWout[i] = 0;
  if (tid == 0) { sb0=0; sb1=0; sb2=0; sb3=0; sb4=0; sb5=0; }

  // ---- per-wave persistent state ----
  short8 bfh[20], bfl[20];    // weight fragments (waves 0-7)
  float bias_r = 0.f;
  float bw[30], kapr[10];
  int myLen = 0;
  if (wave < 8) {
    const int zc = (l15>>2)*512 + jj*32 + wave*4 + (l15&3);   // gate*512 + unit
    #pragma unroll
    for (int kt = 0; kt < 20; ++kt) {
      unsigned short h8[8], l8[8];
      #pragma unroll
      for (int j2 = 0; j2 < 8; ++j2) {
        int k = kt*32 + lhi*8 + j2;
        float v;
        if (k < 512)      v = Wh[(size_t)k*2048 + zc];
        else if (k < 515) v = Wx[(size_t)(k-512)*2048 + zc];
        else if (k < 544) v = 0.f;
        else if (k < 624) v = Wx[(size_t)(3 + (k-544))*2048 + zc];
        else              v = 0.f;
        unsigned short hh = f2b(v);
        h8[j2] = hh; l8[j2] = f2b(v - b2f(hh));
      }
      __builtin_memcpy(&bfh[kt], h8, 16);
      __builtin_memcpy(&bfl[kt], l8, 16);
    }
    bias_r = bias[zc];
  } else {
    #pragma unroll
    for (int c2 = 0; c2 < 30; ++c2) bw[c2] = bwin[c2];
    #pragma unroll
    for (int k2 = 0; k2 < 10; ++k2) kapr[k2] = 0.f;
    myLen = slen[grow];
  }
  __syncthreads();

  float c_reg[4] = {0.f,0.f,0.f,0.f};

  // phase B for output step t-1 (wave 8 only); t in [1..800]
  auto phaseB = [&](int t) {
    while (ald32(haC) < 16*t) __builtin_amdgcn_s_sleep(1);   // h_{t-1} all stored
    i32x4 vh, vl;
    gld16(&vh, hbG + (t&1)*HB_BUF + jj*512 + lane*8);
    gld16(&vl, hbG + (t&1)*HB_BUF + HB_LIMB + jj*512 + lane*8);
    WAIT_VM(0); __builtin_amdgcn_sched_barrier(0);
    unsigned short hh8[8], ll8[8];
    __builtin_memcpy(hh8, &vh, 16); __builtin_memcpy(ll8, &vl, 16);
    float hrow[8];
    #pragma unroll
    for (int i2 = 0; i2 < 8; ++i2) hrow[i2] = b2f(hh8[i2]) + b2f(ll8[i2]);
    float p[30];
    #pragma unroll
    for (int c2 = 0; c2 < 30; ++c2) {
      float4 w0 = *(const float4*)&lWw[c2*520 + lane*8];
      float4 w1 = *(const float4*)&lWw[c2*520 + lane*8 + 4];
      p[c2] = hrow[0]*w0.x + hrow[1]*w0.y + hrow[2]*w0.z + hrow[3]*w0.w
            + hrow[4]*w1.x + hrow[5]*w1.y + hrow[6]*w1.z + hrow[7]*w1.w;
    }
    #pragma unroll
    for (int c2 = 0; c2 < 30; ++c2) {
      float s = p[c2];
      s += __shfl_xor(s, 1);  s += __shfl_xor(s, 2);  s += __shfl_xor(s, 4);
      s += __shfl_xor(s, 8);  s += __shfl_xor(s, 16); s += __shfl_xor(s, 32);
      p[c2] = s + bw[c2];
    }
    float u1 = (float)lane + 1.0f;
    float phi = 0.f;
    #pragma unroll
    for (int k2 = 0; k2 < 10; ++k2) {
      float a  = __expf(p[k2]);
      float be = __expf(p[10+k2]);
      float kn = kapr[k2] + __expf(p[20+k2]);   // reference: phi uses updated kappa
      float d  = kn - u1;
      phi += a * __expf(-be*d*d);
    }
    if (lane >= myLen) phi = 0.f;
    lPhi[lane] = phi;
    out[OUT_PHI + ((size_t)grow*Tt + (t-1))*Uu + lane] = phi;
    #pragma unroll
    for (int k2 = 0; k2 < 10; ++k2) kapr[k2] += __expf(p[20+k2]);
    asm volatile("s_waitcnt lgkmcnt(0)" ::: "memory");
    __builtin_amdgcn_sched_barrier(0);
    #pragma unroll
    for (int half = 0; half < 2; ++half) {
      int c2 = half*64 + lane;
      if (c2 < Cc) {
        float s = 0.f;
        #pragma unroll 8
        for (int u = 0; u < Uu; ++u) s += lPhi[u]*lSent[u*Cc + c2];
        out[OUT_W + ((size_t)grow*Tt + (t-1))*Cc + c2] = s;
        unsigned short w16 = f2b(s);
        lWout[c2]      = w16;                  // hi
        lWout[96 + c2] = f2b(s - b2f(w16));    // lo  (pads 80..95 stay 0)
      }
    }
    asm volatile("s_waitcnt lgkmcnt(0)" ::: "memory");
    __builtin_amdgcn_sched_barrier(0);
    if (lane < 24) {                            // coalesced 16B w stores
      int limb = lane/12, q = lane%12;
      i32x4 v = *(const i32x4*)&lWout[limb*96 + q*8];
      gst16(wbG + jj*192 + limb*96 + q*8, v);
    }
    drain_vm();
    if (lane == 0) aadd32(waC);                 // w_{t-1} ready
  };

  for (int t = 0; t < Tt; ++t) {
    if (wave == 8) {
      if (t >= 1) phaseB(t);
      continue;
    }
    // ================= waves 0-7 =================
    const unsigned short* hb = hbG + (t&1)*HB_BUF;
    if (t > 0) {
      if (wave == 0) {                          // designated h poller (1 line)
        while (ald32(haC) < 16*t) __builtin_amdgcn_s_sleep(1);
      }
      softbar(&sb0, 8*t);                       // releases waves 1-7 after poll
    }
    // stage h_{t-1} (hi+lo) group-wide into LDS A
    {
      const int r0 = tid >> 6;
      const int q0 = lane;
      i32x4 va, vb, vc, vd;
      gld16(&va, hb + r0*512 + q0*8);
      gld16(&vb, hb + (r0+8)*512 + q0*8);
      gld16(&vc, hb + HB_LIMB + r0*512 + q0*8);
      gld16(&vd, hb + HB_LIMB + (r0+8)*512 + q0*8);
      WAIT_VM(0); __builtin_amdgcn_sched_barrier(0);
      *(i32x4*)&lA[r0*ASTR + q0*8]             = va;
      *(i32x4*)&lA[(r0+8)*ASTR + q0*8]         = vb;
      *(i32x4*)&lA[ALIMB + r0*ASTR + q0*8]     = vc;
      *(i32x4*)&lA[ALIMB + (r0+8)*ASTR + q0*8] = vd;
    }
    // x_t -> LDS A (k 512..514)
    if (tid < 48) {
      int row = tid / 3, comp = tid % 3;
      float xv = x[((size_t)(g*16 + row)*Tt + t)*3 + comp];
      unsigned short hh = f2b(xv);
      lA[row*ASTR + 512 + comp]         = hh;
      lA[ALIMB + row*ASTR + 512 + comp] = f2b(xv - b2f(hh));
    }
    softbar(&sb1, 8*(t+1));

    // MFMA h+x region (kt 0..16)
    f32x4 acc0 = {0.f,0.f,0.f,0.f}, acc1 = {0.f,0.f,0.f,0.f};
    const int arow = l15*ASTR + lhi*8;
    #pragma unroll
    for (int kt = 0; kt < 17; ++kt) {
      short8 ah = *(const short8*)&lA[arow + kt*32];
      short8 al = *(const short8*)&lA[ALIMB + arow + kt*32];
      acc0 = __builtin_amdgcn_mfma_f32_16x16x32_bf16(ah, bfh[kt], acc0, 0,0,0);
      acc1 = __builtin_amdgcn_mfma_f32_16x16x32_bf16(ah, bfl[kt], acc1, 0,0,0);
      acc1 = __builtin_amdgcn_mfma_f32_16x16x32_bf16(al, bfh[kt], acc1, 0,0,0);
    }

    // wait w_{t-1} (designated poller = wave1; overlapped with MFMA above)
    if (t > 0 && wave == 1) {
      while (ald32(waC) < 16*t) __builtin_amdgcn_s_sleep(1);
    }
    softbar(&sb2, 8*(t+1));
    // stage w_{t-1} (hi+lo, 96-short rows incl zero pad) into LDS A (k 544..639)
    if (tid < 384) {
      int row = tid / 24, rem = tid % 24, limb = rem / 12, q = rem % 12;
      i32x4 v;
      gld16(&v, wbG + row*192 + limb*96 + q*8);
      WAIT_VM(0); __builtin_amdgcn_sched_barrier(0);
      *(i32x4*)&lA[limb*ALIMB + row*ASTR + 544 + q*8] = v;
    }
    softbar(&sb3, 8*(t+1));

    // MFMA w region (kt 17..19)
    #pragma unroll
    for (int kt = 17; kt < 20; ++kt) {
      short8 ah = *(const short8*)&lA[arow + kt*32];
      short8 al = *(const short8*)&lA[ALIMB + arow + kt*32];
      acc0 = __builtin_amdgcn_mfma_f32_16x16x32_bf16(ah, bfh[kt], acc0, 0,0,0);
      acc1 = __builtin_amdgcn_mfma_f32_16x16x32_bf16(ah, bfl[kt], acc1, 0,0,0);
      acc1 = __builtin_amdgcn_mfma_f32_16x16x32_bf16(al, bfh[kt], acc1, 0,0,0);
    }

    // gates -> h_t (to LDS staging + out)
    #pragma unroll
    for (int r = 0; r < 4; ++r) {
      float v   = acc0[r] + acc1[r] + bias_r;
      float t4  = __shfl_xor(v, 4);
      float t8  = __shfl_xor(v, 8);
      float t12 = __shfl_xor(v, 12);
      float ig = sigm(v), fg = sigm(t4), gg = tanh_(t8), og = sigm(t12);
      float cn = fg*c_reg[r] + ig*gg;
      c_reg[r] = cn;
      float h = og*tanh_(cn);
      if (l15 < 4) {
        int ui = wave*4 + l15;        // 0..31 within block
        int rr = lhi*4 + r;           // 0..15
        unsigned short h16 = f2b(h);
        lHout[rr*32 + ui]       = h16;
        lHout[512 + rr*32 + ui] = f2b(h - b2f(h16));
        out[((size_t)(g*16 + rr)*Tt + t)*512 + (jj*32 + ui)] = h;
      }
    }
    softbar(&sb4, 8*(t+1));

    // coalesced 16B h stores: 16 rows x 2 limbs x 4 chunks = 128 stores
    {
      unsigned short* hbn = hbG + ((t+1)&1)*HB_BUF;
      if (tid < 128) {
        int rr = tid >> 3, limb = (tid >> 2) & 1, q = tid & 3;
        i32x4 v = *(const i32x4*)&lHout[limb*512 + rr*32 + q*8];
        gst16(hbn + limb*HB_LIMB + rr*512 + jj*32 + q*8, v);
        drain_vm();
      }
    }
    softbar(&sb5, 8*(t+1));
    if (tid == 0) aadd32(haC);        // h_t ready
  }

  // epilogue: phi/w for t=799
  if (wave == 8) phaseB(Tt);
}

extern "C" void kernel_launch(void* const* d_in, const int* in_sizes, int n_in,
                              void* d_out, int out_size, void* d_ws, size_t ws_size,
                              hipStream_t stream) {
  (void)in_sizes; (void)n_in; (void)out_size;
  if (ws_size < WS_NEED) return;
  const float* x    = (const float*)d_in[0];
  const float* sent = (const float*)d_in[1];
  const int*   sl   = (const int*)d_in[2];
  const float* Wx   = (const float*)d_in[3];
  const float* Wh   = (const float*)d_in[4];
  const float* bias = (const float*)d_in[5];
  const float* Wwin = (const float*)d_in[6];
  const float* bwin = (const float*)d_in[7];

  char* ws = (char*)d_ws;
  unsigned short* hbuf = (unsigned short*)(ws + WS_HBUF);
  unsigned short* wbuf = (unsigned short*)(ws + WS_WBUF);
  int* fa = (int*)(ws + WS_FA);
  int* fb = (int*)(ws + WS_FB);
  float* out = (float*)d_out;

  prep<<<1122, 256, 0, stream>>>(hbuf, wbuf, fa, fb);
  rnn_main<<<NBLK, 576, 0, stream>>>(x, sent, sl, bias, bwin, Wwin, Wx, Wh,
                                     hbuf, wbuf, fa, fb, out);
}